// Round 2
// baseline (97.804 us; speedup 1.0000x reference)
//
#include <hip/hip_runtime.h>
#include <hip/hip_bf16.h>

#define BB 4
#define TT 2048
#define CC 1024
#define HH 64

typedef __attribute__((ext_vector_type(8))) unsigned short ushort8;
typedef __attribute__((ext_vector_type(4))) unsigned short ushort4v;
typedef __attribute__((ext_vector_type(8))) __bf16 bf16x8;
typedef __attribute__((ext_vector_type(4))) float float4v;

static __device__ __forceinline__ unsigned short f2bf(float f) {
    // round-to-nearest-even f32 -> bf16
    unsigned int u = __builtin_bit_cast(unsigned int, f);
    u += 0x7fffu + ((u >> 16) & 1u);
    return (unsigned short)(u >> 16);
}

static __device__ __forceinline__ float4v mfma16(ushort8 a, ushort8 b, float4v c) {
    return __builtin_amdgcn_mfma_f32_16x16x32_bf16(
        __builtin_bit_cast(bf16x8, a), __builtin_bit_cast(bf16x8, b), c, 0, 0, 0);
}

// ---------------------------------------------------------------------------
// Kernel 0: convert W (f32 [C][H]) -> W^T bf16 [3][H][C] (k-contiguous) once.
// 192 blocks: y = b>>6 (q,k,v), n = b&63. Thread t covers k = 4t..4t+3.
// ---------------------------------------------------------------------------
__global__ __launch_bounds__(256) void wconv_kernel(
    const float* __restrict__ Wq, const float* __restrict__ Wk,
    const float* __restrict__ Wv, unsigned short* __restrict__ wt)
{
    const int bidx = blockIdx.x;
    const int y = bidx >> 6, n = bidx & 63;
    const float* __restrict__ W = (y == 0) ? Wq : (y == 1) ? Wk : Wv;
    const int k0 = threadIdx.x << 2;
    ushort4v p;
#pragma unroll
    for (int i = 0; i < 4; ++i) p[i] = f2bf(W[(size_t)(k0 + i) * HH + n]);
    *(ushort4v*)&wt[((size_t)y * HH + n) * CC + k0] = p;
}

// ---------------------------------------------------------------------------
// Kernel 1: fused q/k/v projection. One pass over x (32 rows/block, 256 blk).
// x staged bf16 in LDS; W^T fragments read directly from global (L2-hot bf16).
// 4 waves: wave = (m-tile mw in 0..1) x (n-half nh in 0..1); 6 n-tiles/wave
// covering q|k|v concatenated (12 tiles of 16 cols). q scaled by 1/8.
// v written TRANSPOSED vT[b][h][t] for the attention PV A-operand.
// ---------------------------------------------------------------------------
__global__ __launch_bounds__(256) void proj_kernel(
    const float* __restrict__ x, const unsigned short* __restrict__ wt,
    unsigned short* __restrict__ qo, unsigned short* __restrict__ ko,
    unsigned short* __restrict__ vo)
{
    __shared__ __align__(16) unsigned short xs[32][72];  // 32 rows x 64 k, pad->72

    const int row0 = blockIdx.x * 32;
    const int tid = threadIdx.x;
    const int lane = tid & 63;
    const int w = tid >> 6;
    const int l15 = lane & 15;
    const int g = lane >> 4;
    const int mw = w & 1, nh = w >> 1;
    const int srow = tid >> 3, sko = (tid & 7) << 3;

    float4v acc[6];
#pragma unroll
    for (int i = 0; i < 6; ++i) acc[i] = (float4v)0.0f;

    for (int k0 = 0; k0 < CC; k0 += 64) {
        {   // stage x tile (32 x 64) -> bf16 LDS, coalesced
            const float* src = x + (size_t)(row0 + srow) * CC + (k0 + sko);
            float4v a = *(const float4v*)src;
            float4v b = *(const float4v*)(src + 4);
            ushort8 p;
#pragma unroll
            for (int i = 0; i < 4; ++i) { p[i] = f2bf(a[i]); p[4 + i] = f2bf(b[i]); }
            *(ushort8*)&xs[srow][sko] = p;
        }
        __syncthreads();
        ushort8 a0 = *(const ushort8*)&xs[16 * mw + l15][8 * g];
        ushort8 a1 = *(const ushort8*)&xs[16 * mw + l15][32 + 8 * g];
#pragma unroll
        for (int j = 0; j < 6; ++j) {
            const int nt = 6 * nh + j, y = nt >> 2, nf = nt & 3;
            const unsigned short* wp = wt + ((size_t)y * HH + 16 * nf + l15) * CC + k0 + 8 * g;
            acc[j] = mfma16(a0, *(const ushort8*)wp, acc[j]);
            acc[j] = mfma16(a1, *(const ushort8*)(wp + 32), acc[j]);
        }
        __syncthreads();
    }

    // C/D layout: col = lane&15 (n within tile), row = 4g + reg (m)
    const int rbase = row0 + 16 * mw + 4 * g;
#pragma unroll
    for (int j = 0; j < 6; ++j) {
        const int nt = 6 * nh + j, y = nt >> 2, nf = nt & 3;
        if (y == 0) {
#pragma unroll
            for (int r = 0; r < 4; ++r)
                qo[(size_t)(rbase + r) * HH + 16 * nf + l15] = f2bf(acc[j][r] * 0.125f);
        } else if (y == 1) {
#pragma unroll
            for (int r = 0; r < 4; ++r)
                ko[(size_t)(rbase + r) * HH + 16 * nf + l15] = f2bf(acc[j][r]);
        } else {
            const int bidx = rbase >> 11;       // 32-row blocks never straddle batches
            const int t0 = rbase & (TT - 1);
            ushort4v pv;
#pragma unroll
            for (int r = 0; r < 4; ++r) pv[r] = f2bf(acc[j][r]);
            *(ushort4v*)&vo[((size_t)bidx * HH + 16 * nf + l15) * TT + t0] = pv;
        }
    }
}

// ---------------------------------------------------------------------------
// Kernel 2: causal flash attention. 8 waves/block; all waves share the same
// 16 queries, each takes KV chunks strided (w, w+8, ...) then partials
// (m,l,o) merge via LDS. Swapped QK^T keeps softmax in registers
// (2 shfl_xor); PV reuses the S/P register layout as B-fragment with V^T
// gathered under the same k-permutation.
// ---------------------------------------------------------------------------
__global__ __launch_bounds__(512) void attn_kernel(
    const unsigned short* __restrict__ qw,
    const unsigned short* __restrict__ kw,
    const unsigned short* __restrict__ vw,
    float* __restrict__ out)
{
    __shared__ float om[8][16], ol[8][16];
    __shared__ __align__(16) float oo[8][16][64];

    const int idx = blockIdx.x;
    const int b = idx & (BB - 1);
    const int qt = (TT / 16 - 1) - (idx >> 2);  // heavy tiles dispatched first
    const int q0 = qt << 4;
    const int tid = threadIdx.x;
    const int w = tid >> 6;
    const int lane = tid & 63;
    const int l15 = lane & 15;
    const int g = lane >> 4;
    const int q = q0 + l15;

    const unsigned short* qrow = qw + (size_t)(b * TT + q) * HH + 8 * g;
    ushort8 qf0 = *(const ushort8*)qrow;
    ushort8 qf1 = *(const ushort8*)(qrow + 32);

    const unsigned short* kb = kw + (size_t)b * TT * HH;
    const unsigned short* vb = vw + (size_t)b * HH * TT;

    float m_run = -3.0e38f, l_run = 0.0f;
    float4v o[4];
#pragma unroll
    for (int i = 0; i < 4; ++i) o[i] = (float4v)0.0f;

    const int ks_end = q0 + 16;
    for (int kv0 = 32 * w; kv0 < ks_end; kv0 += 256) {
        const unsigned short* kr = kb + (size_t)(kv0 + l15) * HH + 8 * g;
        ushort8 ak00 = *(const ushort8*)kr;
        ushort8 ak01 = *(const ushort8*)(kr + 32);
        ushort8 ak10 = *(const ushort8*)(kr + 16 * HH);
        ushort8 ak11 = *(const ushort8*)(kr + 16 * HH + 32);

        float4v s0 = (float4v)0.0f, s1 = (float4v)0.0f;  // S^T: lane=q, reg=key
        s0 = mfma16(ak00, qf0, s0);
        s0 = mfma16(ak01, qf1, s0);
        s1 = mfma16(ak10, qf0, s1);
        s1 = mfma16(ak11, qf1, s1);

        if (kv0 + 31 > q0) {  // partial tile: causal mask
            const int kbase0 = kv0 + 4 * g;
#pragma unroll
            for (int r = 0; r < 4; ++r) {
                if (kbase0 + r > q) s0[r] = -1e30f;
                if (kbase0 + 16 + r > q) s1[r] = -1e30f;
            }
        }

        float mt = s0[0];
#pragma unroll
        for (int r = 1; r < 4; ++r) mt = fmaxf(mt, s0[r]);
#pragma unroll
        for (int r = 0; r < 4; ++r) mt = fmaxf(mt, s1[r]);
        mt = fmaxf(mt, __shfl_xor(mt, 16, 64));
        mt = fmaxf(mt, __shfl_xor(mt, 32, 64));

        const float m_new = fmaxf(m_run, mt);
        const float scale = __expf(m_run - m_new);
        float p0[4], p1[4];
        float sum = 0.0f;
#pragma unroll
        for (int r = 0; r < 4; ++r) {
            p0[r] = __expf(s0[r] - m_new);
            p1[r] = __expf(s1[r] - m_new);
            sum += p0[r] + p1[r];
        }
        sum += __shfl_xor(sum, 16, 64);
        sum += __shfl_xor(sum, 32, 64);
        l_run = l_run * scale + sum;
        m_run = m_new;
#pragma unroll
        for (int i = 0; i < 4; ++i) o[i] *= scale;

        ushort8 bp;  // P^T fragment: kappa(g,j) = 16*(j>>2) + 4g + (j&3)
#pragma unroll
        for (int r = 0; r < 4; ++r) { bp[r] = f2bf(p0[r]); bp[4 + r] = f2bf(p1[r]); }

#pragma unroll
        for (int ht = 0; ht < 4; ++ht) {
            const unsigned short* vp = vb + (size_t)(16 * ht + l15) * TT + kv0 + 4 * g;
            ushort4v v0 = *(const ushort4v*)vp;
            ushort4v v1 = *(const ushort4v*)(vp + 16);
            ushort8 av;
#pragma unroll
            for (int r = 0; r < 4; ++r) { av[r] = v0[r]; av[4 + r] = v1[r]; }
            o[ht] = mfma16(av, bp, o[ht]);
        }
    }

    // publish partials: m,l per query (dup across g -> lane<16 writes), o full
    if (lane < 16) { om[w][lane] = m_run; ol[w][lane] = l_run; }
#pragma unroll
    for (int ht = 0; ht < 4; ++ht)
        *(float4v*)&oo[w][l15][16 * ht + 4 * g] = o[ht];
    __syncthreads();

    // merge 8 partials: 1024 (q,h) elems over 512 threads
#pragma unroll 2
    for (int e = tid; e < 16 * HH; e += 512) {
        const int qq = e >> 6, h = e & 63;
        float mstar = om[0][qq];
#pragma unroll
        for (int w2 = 1; w2 < 8; ++w2) mstar = fmaxf(mstar, om[w2][qq]);
        float lsum = 0.0f, osum = 0.0f;
#pragma unroll
        for (int w2 = 0; w2 < 8; ++w2) {
            const float al = __expf(om[w2][qq] - mstar);
            lsum += al * ol[w2][qq];
            osum += al * oo[w2][qq][h];
        }
        out[((size_t)b * TT + q0 + qq) * HH + h] = osum / lsum;
    }
}

extern "C" void kernel_launch(void* const* d_in, const int* in_sizes, int n_in,
                              void* d_out, int out_size, void* d_ws, size_t ws_size,
                              hipStream_t stream) {
    // setup_inputs order: x, Wk, Wq, Wv
    const float* x  = (const float*)d_in[0];
    const float* Wk = (const float*)d_in[1];
    const float* Wq = (const float*)d_in[2];
    const float* Wv = (const float*)d_in[3];

    // ws: q bf16 [B*T][64] | k bf16 [B*T][64] | vT bf16 [B][64][T] | W^T bf16 [3][64][1024]
    unsigned short* q_ws  = (unsigned short*)d_ws;
    unsigned short* k_ws  = q_ws + (size_t)BB * TT * HH;
    unsigned short* vt_ws = k_ws + (size_t)BB * TT * HH;
    unsigned short* wt_ws = vt_ws + (size_t)BB * TT * HH;

    wconv_kernel<<<192, 256, 0, stream>>>(Wq, Wk, Wv, wt_ws);
    proj_kernel<<<BB * TT / 32, 256, 0, stream>>>(x, wt_ws, q_ws, k_ws, vt_ws);
    attn_kernel<<<BB * TT / 16, 512, 0, stream>>>(q_ws, k_ws, vt_ws, (float*)d_out);
}